// Round 1
// 419.495 us; speedup vs baseline: 1.1408x; 1.1408x over previous
//
#include <hip/hip_runtime.h>

// MHA: QKV GEMM (fp32 in, bf16 MFMA) -> RoPE -> MFMA flash attention (fp32 out)
// B=2 S=2048 E=2048 NH=16 HD=128 ROTARY=32 base=1e4 NEG_INF=-1e4
#define B_    2
#define S_    2048
#define E_    2048
#define NH_   16
#define HD_   128
#define NQKV_ 6144
#define M_    4096

typedef short bf16x8 __attribute__((ext_vector_type(8)));   // 8 bf16 (4 VGPRs)
typedef float f32x4  __attribute__((ext_vector_type(4)));   // MFMA C/D

__device__ inline float b2f(unsigned short u) {
    return __uint_as_float(((unsigned int)u) << 16);
}
__device__ inline unsigned short f2b(float f) {             // RNE f32->bf16
    unsigned int x = __float_as_uint(f);
    x = x + 0x7fffu + ((x >> 16) & 1u);
    return (unsigned short)(x >> 16);
}
__device__ inline unsigned int pk2(float lo, float hi) {
    return (unsigned int)f2b(lo) | ((unsigned int)f2b(hi) << 16);
}

// ---------------------------------------------------------------------------
// Kernel 1: QKV = X(4096x2048 fp32) * W^T + bias. bf16 MFMA, reg prefetch.
// q/k/v all row-major [B][NH][S][HD]. (unchanged)
// ---------------------------------------------------------------------------
__global__ __launch_bounds__(256, 2) void qkv_gemm(
    const float* __restrict__ X,
    const float* __restrict__ W,
    const float* __restrict__ bias,
    unsigned short* __restrict__ qb,
    unsigned short* __restrict__ kb,
    unsigned short* __restrict__ vb)
{
    __shared__ __align__(16) unsigned short As[128 * 32];
    __shared__ __align__(16) unsigned short Bs[128 * 32];

    const int t    = threadIdx.x;
    const int lane = t & 63;
    const int wave = t >> 6;
    const int m0   = blockIdx.y * 128;
    const int n0   = blockIdx.x * 128;
    const int wm   = (wave >> 1) * 64;
    const int wn   = (wave & 1) * 64;
    const int quad = lane >> 4;
    const int l16  = lane & 15;

    const int srow = t >> 2;          // 0..63
    const int scol = (t & 3) * 8;     // 0,8,16,24

    const float* Ap = X + (m0 + srow) * E_ + scol;
    const float* Bp = W + (n0 + srow) * E_ + scol;

    f32x4 acc[4][4];
    #pragma unroll
    for (int i = 0; i < 4; i++)
        #pragma unroll
        for (int j = 0; j < 4; j++)
            #pragma unroll
            for (int r = 0; r < 4; r++) acc[i][j][r] = 0.0f;

    float4 a00 = *(const float4*)(Ap);
    float4 a01 = *(const float4*)(Ap + 4);
    float4 a10 = *(const float4*)(Ap + 64 * E_);
    float4 a11 = *(const float4*)(Ap + 64 * E_ + 4);
    float4 b00 = *(const float4*)(Bp);
    float4 b01 = *(const float4*)(Bp + 4);
    float4 b10 = *(const float4*)(Bp + 64 * E_);
    float4 b11 = *(const float4*)(Bp + 64 * E_ + 4);

    for (int k0 = 0; k0 < E_; k0 += 32) {
        __syncthreads();
        {
            uint4 pa0 = { pk2(a00.x, a00.y), pk2(a00.z, a00.w),
                          pk2(a01.x, a01.y), pk2(a01.z, a01.w) };
            uint4 pa1 = { pk2(a10.x, a10.y), pk2(a10.z, a10.w),
                          pk2(a11.x, a11.y), pk2(a11.z, a11.w) };
            uint4 pb0 = { pk2(b00.x, b00.y), pk2(b00.z, b00.w),
                          pk2(b01.x, b01.y), pk2(b01.z, b01.w) };
            uint4 pb1 = { pk2(b10.x, b10.y), pk2(b10.z, b10.w),
                          pk2(b11.x, b11.y), pk2(b11.z, b11.w) };
            *(uint4*)&As[srow * 32 + scol]        = pa0;
            *(uint4*)&As[(srow + 64) * 32 + scol] = pa1;
            *(uint4*)&Bs[srow * 32 + scol]        = pb0;
            *(uint4*)&Bs[(srow + 64) * 32 + scol] = pb1;
        }
        __syncthreads();

        const int kn = k0 + 32;
        if (kn < E_) {
            a00 = *(const float4*)(Ap + kn);
            a01 = *(const float4*)(Ap + kn + 4);
            a10 = *(const float4*)(Ap + kn + 64 * E_);
            a11 = *(const float4*)(Ap + kn + 64 * E_ + 4);
            b00 = *(const float4*)(Bp + kn);
            b01 = *(const float4*)(Bp + kn + 4);
            b10 = *(const float4*)(Bp + kn + 64 * E_);
            b11 = *(const float4*)(Bp + kn + 64 * E_ + 4);
        }

        bf16x8 af[4], bfr[4];
        #pragma unroll
        for (int i = 0; i < 4; i++)
            af[i]  = *(const bf16x8*)&As[(wm + i * 16 + l16) * 32 + quad * 8];
        #pragma unroll
        for (int i = 0; i < 4; i++)
            bfr[i] = *(const bf16x8*)&Bs[(wn + i * 16 + l16) * 32 + quad * 8];

        #pragma unroll
        for (int i = 0; i < 4; i++)
            #pragma unroll
            for (int j = 0; j < 4; j++)
                acc[i][j] = __builtin_amdgcn_mfma_f32_16x16x32_bf16(
                    af[i], bfr[j], acc[i][j], 0, 0, 0);
    }

    #pragma unroll
    for (int j = 0; j < 4; j++) {
        const int n = n0 + wn + j * 16 + l16;           // 0..6143
        const float bv = bias[n];
        const int which = n >> 11;                      // 0=q 1=k 2=v
        const int h = (n >> 7) & 15;
        const int d = n & 127;
        unsigned short* dst = (which == 0) ? qb : ((which == 1) ? kb : vb);
        #pragma unroll
        for (int i = 0; i < 4; i++) {
            #pragma unroll
            for (int r = 0; r < 4; r++) {
                const int m  = m0 + wm + i * 16 + quad * 4 + r;  // 0..4095
                const int bb = m >> 11;
                const int s  = m & (S_ - 1);
                dst[((size_t)(bb * NH_ + h) * S_ + s) * HD_ + d] = f2b(acc[i][j][r] + bv);
            }
        }
    }
}

// ---------------------------------------------------------------------------
// Kernel 2: in-place RoPE on q and k (bf16, fp32 math). Layout [B][NH][S][HD].
// __sincosf: hw v_sin/v_cos path; phase err ~2e-4 rad at s~2048, << bf16 ulp.
// ---------------------------------------------------------------------------
__global__ void rope_inplace(unsigned short* __restrict__ qb,
                             unsigned short* __restrict__ kb)
{
    const int idx = blockIdx.x * 256 + threadIdx.x;     // B*NH*S*16 exactly
    const int i   = idx & 15;
    const int s   = (idx >> 4) & (S_ - 1);
    const int bh  = idx >> 15;
    const float inv = exp2f(-0.83048202372184059f * (float)i); // log2(1e4)/16
    const float ang = (float)s * inv;
    float c, sn;
    __sincosf(ang, &sn, &c);
    const int base = (bh * S_ + s) * HD_;
    {
        float u1 = b2f(qb[base + i]), u2 = b2f(qb[base + i + 16]);
        qb[base + i]      = f2b(u1 * c - u2 * sn);
        qb[base + i + 16] = f2b(u1 * sn + u2 * c);
    }
    {
        float u1 = b2f(kb[base + i]), u2 = b2f(kb[base + i + 16]);
        kb[base + i]      = f2b(u1 * c - u2 * sn);
        kb[base + i + 16] = f2b(u1 * sn + u2 * c);
    }
}

// ---------------------------------------------------------------------------
// Kernel 3: MFMA causal flash attention. Round-6 changes:
//  * GLOBAL heavy-first dispatch: 1-D grid, qt = 15 - (bid>>5), bh = bid&31.
//    All qt=15 (32-tile) blocks launch first; tail is qt=0 (2-tile) blocks.
//    Fixes the 12.4% time-avg occupancy (vs 25% static) caused by heavy
//    blocks being dispatched last for bh>=16. Also bid%8==bh%8 -> same-bh
//    blocks share an XCD L2 for K/V.
//  * softmax in log2 domain (scale,mask pre-multiplied by log2e): each of
//    the 32 exps per tile-iter is a bare v_exp_f32.
//  * lr kept as per-lane partials; 16-lane reduce moved to epilogue
//    (-32 shfl_xor adds per tile-iter).
//  * defer-rescale: skip alpha-exp + 64 of-multiplies when no row max grew
//    (alpha would be exactly 1.0 -> bitwise-identical output).
// Layouts (HW-verified 16x16x32_bf16): A[m=lane&15][k=quad*8+j];
// C/D row=quad*4+reg, col=lane&15.
// ---------------------------------------------------------------------------
#define KSTR 136
#define VSTR 72
#define PSTR 72
#define OSTR 132

__global__ __launch_bounds__(256, 2) void attn_mfma(
    const unsigned short* __restrict__ qb,
    const unsigned short* __restrict__ kb,
    const unsigned short* __restrict__ vb,
    float* __restrict__ out)
{
    union SM {
        struct {
            unsigned short Ks[64 * KSTR];      // 17408 B
            unsigned short Vt[128 * VSTR];     // 18432 B
            unsigned short Ps[4 * 32 * PSTR];  // 18432 B
        } a;
        float Ow[4 * 16 * OSTR];               // 33792 B (epilogue reuse)
    };
    __shared__ __align__(16) SM sm;
    unsigned short* Ks = sm.a.Ks;
    unsigned short* Vt = sm.a.Vt;
    unsigned short* Ps = sm.a.Ps;

    const int bid  = blockIdx.x;
    const int qt   = (S_ / 128 - 1) - (bid >> 5);   // heavy-first, globally
    const int bh   = bid & 31;
    const int b    = bh >> 4;
    const int h    = bh & 15;
    const int t    = threadIdx.x;
    const int lane = t & 63;
    const int w    = t >> 6;
    const int quad = lane >> 4;
    const int l16  = lane & 15;

    const int qb0    = qt * 128;            // block q-row base
    const int wrow0  = qb0 + w * 32;        // wave q-row base (32 rows)
    const int ntiles = 2 * qt + 2;          // K tiles of 64

    unsigned short* Pw = Ps + w * 32 * PSTR;

    // staging maps
    const int krow = t >> 2, kcb = (t & 3) * 32;   // K: row, col-block
    const int vq   = t & 31, vd0 = (t >> 5) * 16;  // V: s-pair, d-block

    // Q A-fragments from global: m-block mb, k = c*32 + quad*8 + j
    bf16x8 qf[2][4];
    #pragma unroll
    for (int mb = 0; mb < 2; mb++) {
        const unsigned short* qp =
            qb + ((size_t)(bh * S_ + wrow0 + mb * 16 + l16)) * HD_ + quad * 8;
        #pragma unroll
        for (int c = 0; c < 4; c++)
            qf[mb][c] = *(const bf16x8*)(qp + c * 32);
    }

    f32x4 of[2][8];
    #pragma unroll
    for (int mb = 0; mb < 2; mb++)
        #pragma unroll
        for (int db = 0; db < 8; db++)
            #pragma unroll
            for (int r = 0; r < 4; r++) of[mb][db][r] = 0.0f;
    float mr[2][4], lr[2][4];
    #pragma unroll
    for (int mb = 0; mb < 2; mb++)
        #pragma unroll
        for (int r = 0; r < 4; r++) { mr[mb][r] = -1e30f; lr[mb][r] = 0.0f; }

    // log2-domain softmax: scale' = (1/sqrt(128))*log2(e), mask' = -1e4*log2(e)
    const float scale2 = 0.12751744459892879f;
    const float mneg2  = -14426.950408889634f;

    // prefetch registers
    uint4 kr[4];
    uint4 v0a, v0b, v1a, v1b;

    auto issue_tile = [&](int kt2) {
        const int s2 = kt2 * 64;
        const unsigned short* kg = kb + ((size_t)(bh * S_ + s2 + krow)) * HD_ + kcb;
        #pragma unroll
        for (int u = 0; u < 4; u++) kr[u] = *(const uint4*)(kg + u * 8);
        const unsigned short* vg = vb + ((size_t)(bh * S_ + s2 + 2 * vq)) * HD_ + vd0;
        v0a = *(const uint4*)(vg);
        v0b = *(const uint4*)(vg + 8);
        v1a = *(const uint4*)(vg + HD_);
        v1b = *(const uint4*)(vg + HD_ + 8);
    };

    issue_tile(0);

    for (int kt = 0; kt < ntiles; kt++) {
        const int s0 = kt * 64;
        __syncthreads();                  // prior iter's LDS readers done
        // ---- K tile -> LDS (row-major, b128)
        #pragma unroll
        for (int u = 0; u < 4; u++)
            *(uint4*)&Ks[krow * KSTR + kcb + u * 8] = kr[u];
        // ---- V tile -> LDS transposed: Vt[d][s], s-pairs packed as b32
        {
            unsigned int r0[8] = { v0a.x, v0a.y, v0a.z, v0a.w,
                                   v0b.x, v0b.y, v0b.z, v0b.w };
            unsigned int r1[8] = { v1a.x, v1a.y, v1a.z, v1a.w,
                                   v1b.x, v1b.y, v1b.z, v1b.w };
            #pragma unroll
            for (int j = 0; j < 16; j++) {
                const int u = j >> 1;
                unsigned int pk;
                if ((j & 1) == 0)
                    pk = (r0[u] & 0xffffu) | (r1[u] << 16);
                else
                    pk = (r0[u] >> 16) | (r1[u] & 0xffff0000u);
                *(unsigned int*)&Vt[(vd0 + j) * VSTR + 2 * vq] = pk;
            }
        }
        __syncthreads();

        if (kt + 1 < ntiles) issue_tile(kt + 1);

        // ---- S = Q K^T : m-blocks x 4 nb; kf reused across m-blocks
        f32x4 sf[2][4];
        #pragma unroll
        for (int mb = 0; mb < 2; mb++)
            #pragma unroll
            for (int nb = 0; nb < 4; nb++)
                #pragma unroll
                for (int r = 0; r < 4; r++) sf[mb][nb][r] = 0.0f;
        #pragma unroll
        for (int c = 0; c < 4; c++) {
            #pragma unroll
            for (int nb = 0; nb < 4; nb++) {
                bf16x8 kf = *(const bf16x8*)&Ks[(nb * 16 + l16) * KSTR + c * 32 + quad * 8];
                #pragma unroll
                for (int mb = 0; mb < 2; mb++)
                    sf[mb][nb] = __builtin_amdgcn_mfma_f32_16x16x32_bf16(
                        qf[mb][c], kf, sf[mb][nb], 0, 0, 0);
            }
        }

        // ---- scale + causal mask, log2 domain
        const bool need_mask = (s0 + 63 > wrow0);
        #pragma unroll
        for (int mb = 0; mb < 2; mb++) {
            const int qr0 = wrow0 + mb * 16 + quad * 4;
            #pragma unroll
            for (int nb = 0; nb < 4; nb++) {
                const int kcol = s0 + nb * 16 + l16;
                #pragma unroll
                for (int r = 0; r < 4; r++) {
                    float s = sf[mb][nb][r] * scale2;
                    if (need_mask && kcol > qr0 + r) s += mneg2;
                    sf[mb][nb][r] = s;
                }
            }
        }

        // ---- online softmax per m-block (max reduce over 16-lane group;
        //      lr kept as per-lane partials; rescale deferred when max static)
        #pragma unroll
        for (int mb = 0; mb < 2; mb++) {
            float mt4[4];
            #pragma unroll
            for (int r = 0; r < 4; r++) {
                float mt = fmaxf(fmaxf(sf[mb][0][r], sf[mb][1][r]),
                                 fmaxf(sf[mb][2][r], sf[mb][3][r]));
                mt = fmaxf(mt, __shfl_xor(mt, 1));
                mt = fmaxf(mt, __shfl_xor(mt, 2));
                mt = fmaxf(mt, __shfl_xor(mt, 4));
                mt = fmaxf(mt, __shfl_xor(mt, 8));
                mt4[r] = mt;
            }
            const bool grew = (mt4[0] > mr[mb][0]) || (mt4[1] > mr[mb][1]) ||
                              (mt4[2] > mr[mb][2]) || (mt4[3] > mr[mb][3]);
            if (__any(grew)) {
                float alpha[4];
                #pragma unroll
                for (int r = 0; r < 4; r++) {
                    const float mnew = fmaxf(mr[mb][r], mt4[r]);
                    alpha[r] = __builtin_amdgcn_exp2f(mr[mb][r] - mnew);
                    mr[mb][r] = mnew;
                    lr[mb][r] *= alpha[r];
                }
                #pragma unroll
                for (int db = 0; db < 8; db++)
                    #pragma unroll
                    for (int r = 0; r < 4; r++) of[mb][db][r] *= alpha[r];
            }
            #pragma unroll
            for (int r = 0; r < 4; r++) {
                float rs = 0.0f;
                #pragma unroll
                for (int nb = 0; nb < 4; nb++) {
                    float p = __builtin_amdgcn_exp2f(sf[mb][nb][r] - mr[mb][r]);
                    sf[mb][nb][r] = p;
                    rs += p;
                }
                lr[mb][r] += rs;       // per-lane partial; reduced in epilogue
            }

            // P: C-layout -> wave-private LDS [m][s]
            #pragma unroll
            for (int nb = 0; nb < 4; nb++)
                #pragma unroll
                for (int r = 0; r < 4; r++)
                    Pw[(mb * 16 + quad * 4 + r) * PSTR + nb * 16 + l16] =
                        f2b(sf[mb][nb][r]);
        }

        // ---- O += P V : vf reused across m-blocks
        #pragma unroll
        for (int kc = 0; kc < 2; kc++) {
            bf16x8 pf[2];
            #pragma unroll
            for (int mb = 0; mb < 2; mb++)
                pf[mb] = *(const bf16x8*)&Pw[(mb * 16 + l16) * PSTR + kc * 32 + quad * 8];
            #pragma unroll
            for (int db = 0; db < 8; db++) {
                bf16x8 vf = *(const bf16x8*)&Vt[(db * 16 + l16) * VSTR + kc * 32 + quad * 8];
                #pragma unroll
                for (int mb = 0; mb < 2; mb++)
                    of[mb][db] = __builtin_amdgcn_mfma_f32_16x16x32_bf16(
                        pf[mb], vf, of[mb][db], 0, 0, 0);
            }
        }
    }

    // ---- epilogue: lane-reduce lr, normalize, LDS transpose, float4 stores.
    // One m-block per pass; barrier between passes (union WAR safety).
    float* Ow = sm.Ow + w * 16 * OSTR;     // wave-private 16x132 fp32
    #pragma unroll
    for (int mb = 0; mb < 2; mb++) {
        __syncthreads();                   // readers of Ks/Vt/Ps (or pass 0) done
        float inv[4];
        #pragma unroll
        for (int r = 0; r < 4; r++) {
            float ls = lr[mb][r];
            ls += __shfl_xor(ls, 1);
            ls += __shfl_xor(ls, 2);
            ls += __shfl_xor(ls, 4);
            ls += __shfl_xor(ls, 8);
            inv[r] = 1.0f / ls;
        }
        #pragma unroll
        for (int db = 0; db < 8; db++)
            #pragma unroll
            for (int r = 0; r < 4; r++)
                Ow[(quad * 4 + r) * OSTR + db * 16 + l16] = of[mb][db][r] * inv[r];
        #pragma unroll
        for (int rg = 0; rg < 4; rg++) {
            const int rowl = rg * 4 + quad;
            float* op = out + ((size_t)(b * S_ + wrow0 + mb * 16 + rowl)) * E_ + h * HD_;
            #pragma unroll
            for (int u = 0; u < 2; u++) {
                float4 v4 = *(const float4*)&Ow[rowl * OSTR + u * 64 + l16 * 4];
                *(float4*)(op + u * 64 + l16 * 4) = v4;
            }
        }
    }
}

// ---------------------------------------------------------------------------
extern "C" void kernel_launch(void* const* d_in, const int* in_sizes, int n_in,
                              void* d_out, int out_size, void* d_ws, size_t ws_size,
                              hipStream_t stream)
{
    const float* x    = (const float*)d_in[0];   // fp32 (B,S,E)
    const float* W    = (const float*)d_in[1];   // fp32 (6144,2048)
    const float* bias = (const float*)d_in[2];   // fp32 (6144,)
    float* out = (float*)d_out;                  // fp32 (B,S,E)

    const size_t per = (size_t)B_ * NH_ * S_ * HD_;               // 8388608
    unsigned short* qb = (unsigned short*)d_ws;                   // [B][NH][S][HD]
    unsigned short* kb = qb + per;                                // [B][NH][S][HD]
    unsigned short* vb = kb + per;                                // [B][NH][S][HD]

    dim3 gemm_grid(NQKV_ / 128, M_ / 128);                        // 48 x 32
    qkv_gemm<<<gemm_grid, 256, 0, stream>>>(x, W, bias, qb, kb, vb);

    rope_inplace<<<(B_ * NH_ * S_ * 16) / 256, 256, 0, stream>>>(qb, kb);

    attn_mfma<<<dim3((S_ / 128) * B_ * NH_), 256, 0, stream>>>(qb, kb, vb, out);
}

// Round 2
// 381.575 us; speedup vs baseline: 1.2541x; 1.0994x over previous
//
#include <hip/hip_runtime.h>

// MHA: cvt fp32->bf16 -> QKV GEMM (bf16 MFMA, global_load_lds, fused RoPE)
//      -> MFMA flash attention (fp32 out)
// B=2 S=2048 E=2048 NH=16 HD=128 ROTARY=32 base=1e4 NEG_INF=-1e4
#define B_    2
#define S_    2048
#define E_    2048
#define NH_   16
#define HD_   128
#define NQKV_ 6144
#define M_    4096
#define XN_   (M_ * E_)          // 8388608 X elements

typedef short bf16x8 __attribute__((ext_vector_type(8)));   // 8 bf16 (4 VGPRs)
typedef float f32x4  __attribute__((ext_vector_type(4)));   // MFMA C/D

typedef const __attribute__((address_space(1))) void* gas_t; // global addrspace
typedef __attribute__((address_space(3))) void*       las_t; // LDS addrspace

__device__ inline float b2f(unsigned short u) {
    return __uint_as_float(((unsigned int)u) << 16);
}
__device__ inline unsigned short f2b(float f) {             // RNE f32->bf16
    unsigned int x = __float_as_uint(f);
    x = x + 0x7fffu + ((x >> 16) & 1u);
    return (unsigned short)(x >> 16);
}
__device__ inline unsigned int pk2(float lo, float hi) {
    return (unsigned int)f2b(lo) | ((unsigned int)f2b(hi) << 16);
}

// ---------------------------------------------------------------------------
// Kernel 0: one-shot fp32 -> bf16 of X (8.39M) and W (12.58M) into workspace.
// 8 elems/thread, float4 loads, uint4 store. ~126 MB traffic ~= 20 us.
// ---------------------------------------------------------------------------
__global__ __launch_bounds__(256) void cvt_bf16(
    const float* __restrict__ X,
    const float* __restrict__ W,
    unsigned short* __restrict__ O)      // [XN_ of X][W follows]
{
    const long i = (long)(blockIdx.x * 256 + threadIdx.x) * 8;
    const float* src = (i < XN_) ? (X + i) : (W + (i - XN_));
    const float4 a = *(const float4*)(src);
    const float4 b = *(const float4*)(src + 4);
    uint4 o = { pk2(a.x, a.y), pk2(a.z, a.w), pk2(b.x, b.y), pk2(b.z, b.w) };
    *(uint4*)(O + i) = o;
}

// ---------------------------------------------------------------------------
// Kernel 1: QKV = Xb(4096x2048 bf16) * Wb^T + bias, RoPE fused in epilogue.
// m97 structure: 128x128 tile, BK=32, double-buffered LDS via
// global_load_lds width=16 (no VALU staging, no LDS write conflicts).
// q/k/v row-major [B][NH][S][HD] bf16.
// ---------------------------------------------------------------------------
__global__ __launch_bounds__(256, 2) void qkv_gemm(
    const unsigned short* __restrict__ Xb,   // bf16 [4096][2048]
    const unsigned short* __restrict__ Wb,   // bf16 [6144][2048]
    const float* __restrict__ bias,
    unsigned short* __restrict__ qb,
    unsigned short* __restrict__ kb,
    unsigned short* __restrict__ vb)
{
    __shared__ __align__(16) unsigned short As[2][128 * 32];  // 2 x 8 KB
    __shared__ __align__(16) unsigned short Bs[2][128 * 32];  // 2 x 8 KB

    const int t    = threadIdx.x;
    const int lane = t & 63;
    const int w    = t >> 6;
    const int m0   = blockIdx.y * 128;
    const int n0   = blockIdx.x * 128;
    const int wm   = (w >> 1) * 64;
    const int wn   = (w & 1) * 64;
    const int quad = lane >> 4;
    const int l16  = lane & 15;

    // global_load_lds lane map: 1024B chunk = 16 rows x 64B; lane l covers
    // row l>>2, col-block (l&3)*8 bf16. LDS dest = chunk base + lane*16 (HW).
    const unsigned short* Ag = Xb + (size_t)(m0 + (lane >> 2)) * E_ + (lane & 3) * 8;
    const unsigned short* Bg = Wb + (size_t)(n0 + (lane >> 2)) * E_ + (lane & 3) * 8;

    auto stage = [&](int bsel, int k0) {
        #pragma unroll
        for (int u = 0; u < 2; u++) {
            const int r0 = (w * 2 + u) * 16;               // wave-uniform
            __builtin_amdgcn_global_load_lds(
                (gas_t)(Ag + (size_t)r0 * E_ + k0),
                (las_t)&As[bsel][r0 * 32], 16, 0, 0);
            __builtin_amdgcn_global_load_lds(
                (gas_t)(Bg + (size_t)r0 * E_ + k0),
                (las_t)&Bs[bsel][r0 * 32], 16, 0, 0);
        }
    };

    f32x4 acc[4][4];
    #pragma unroll
    for (int i = 0; i < 4; i++)
        #pragma unroll
        for (int j = 0; j < 4; j++)
            #pragma unroll
            for (int r = 0; r < 4; r++) acc[i][j][r] = 0.0f;

    stage(0, 0);
    __syncthreads();            // drains vmcnt before s_barrier (compiler)
    int cur = 0;

    for (int k0 = 0; k0 < E_; k0 += 32) {
        if (k0 + 32 < E_) stage(cur ^ 1, k0 + 32);   // prefetch next K-tile

        bf16x8 af[4], bfr[4];
        #pragma unroll
        for (int i = 0; i < 4; i++)
            af[i]  = *(const bf16x8*)&As[cur][(wm + i * 16 + l16) * 32 + quad * 8];
        #pragma unroll
        for (int i = 0; i < 4; i++)
            bfr[i] = *(const bf16x8*)&Bs[cur][(wn + i * 16 + l16) * 32 + quad * 8];

        #pragma unroll
        for (int i = 0; i < 4; i++)
            #pragma unroll
            for (int j = 0; j < 4; j++)
                acc[i][j] = __builtin_amdgcn_mfma_f32_16x16x32_bf16(
                    af[i], bfr[j], acc[i][j], 0, 0, 0);

        __syncthreads();        // drain prefetch vmcnt + readers done
        cur ^= 1;
    }

    // ---- epilogue: bias, fused RoPE (d<32 pairs live in acc[i][0]/acc[i][1]
    // of the same thread when wn==0), bf16 stores.
    const int nb0   = n0 + wn;                    // 128-aligned half-tile base
    const int which = nb0 >> 11;                  // 0=q 1=k 2=v (const/block)
    const int h     = (nb0 >> 7) & 15;
    unsigned short* dst = (which == 0) ? qb : ((which == 1) ? kb : vb);

    float bv[4];
    #pragma unroll
    for (int j = 0; j < 4; j++) bv[j] = bias[nb0 + j * 16 + l16];
    #pragma unroll
    for (int i = 0; i < 4; i++)
        #pragma unroll
        for (int j = 0; j < 4; j++)
            #pragma unroll
            for (int r = 0; r < 4; r++) acc[i][j][r] += bv[j];

    if (wn == 0 && which < 2) {                   // rope on q/k, d in [0,32)
        const float inv = exp2f(-0.83048202372184059f * (float)l16); // 1e4^(-d/16)
        #pragma unroll
        for (int i = 0; i < 4; i++) {
            #pragma unroll
            for (int r = 0; r < 4; r++) {
                const int m = m0 + wm + i * 16 + quad * 4 + r;
                const int s = m & (S_ - 1);
                float c, sn;
                __sincosf((float)s * inv, &sn, &c);
                const float u1 = acc[i][0][r], u2 = acc[i][1][r];
                acc[i][0][r] = u1 * c - u2 * sn;
                acc[i][1][r] = u1 * sn + u2 * c;
            }
        }
    }

    #pragma unroll
    for (int j = 0; j < 4; j++) {
        const int d = wn + j * 16 + l16;
        #pragma unroll
        for (int i = 0; i < 4; i++) {
            #pragma unroll
            for (int r = 0; r < 4; r++) {
                const int m  = m0 + wm + i * 16 + quad * 4 + r;  // 0..4095
                const int bb = m >> 11;
                const int s  = m & (S_ - 1);
                dst[((size_t)(bb * NH_ + h) * S_ + s) * HD_ + d] = f2b(acc[i][j][r]);
            }
        }
    }
}

// ---------------------------------------------------------------------------
// Kernel 2: MFMA causal flash attention (unchanged from round 1 — it fell out
// of the top-5; global heavy-first dispatch + log2 softmax + defer-rescale).
// Layouts (HW-verified 16x16x32_bf16): A[m=lane&15][k=quad*8+j];
// C/D row=quad*4+reg, col=lane&15.
// ---------------------------------------------------------------------------
#define KSTR 136
#define VSTR 72
#define PSTR 72
#define OSTR 132

__global__ __launch_bounds__(256, 2) void attn_mfma(
    const unsigned short* __restrict__ qb,
    const unsigned short* __restrict__ kb,
    const unsigned short* __restrict__ vb,
    float* __restrict__ out)
{
    union SM {
        struct {
            unsigned short Ks[64 * KSTR];      // 17408 B
            unsigned short Vt[128 * VSTR];     // 18432 B
            unsigned short Ps[4 * 32 * PSTR];  // 18432 B
        } a;
        float Ow[4 * 16 * OSTR];               // 33792 B (epilogue reuse)
    };
    __shared__ __align__(16) SM sm;
    unsigned short* Ks = sm.a.Ks;
    unsigned short* Vt = sm.a.Vt;
    unsigned short* Ps = sm.a.Ps;

    const int bid  = blockIdx.x;
    const int qt   = (S_ / 128 - 1) - (bid >> 5);   // heavy-first, globally
    const int bh   = bid & 31;
    const int b    = bh >> 4;
    const int h    = bh & 15;
    const int t    = threadIdx.x;
    const int lane = t & 63;
    const int w    = t >> 6;
    const int quad = lane >> 4;
    const int l16  = lane & 15;

    const int qb0    = qt * 128;            // block q-row base
    const int wrow0  = qb0 + w * 32;        // wave q-row base (32 rows)
    const int ntiles = 2 * qt + 2;          // K tiles of 64

    unsigned short* Pw = Ps + w * 32 * PSTR;

    // staging maps
    const int krow = t >> 2, kcb = (t & 3) * 32;   // K: row, col-block
    const int vq   = t & 31, vd0 = (t >> 5) * 16;  // V: s-pair, d-block

    // Q A-fragments from global: m-block mb, k = c*32 + quad*8 + j
    bf16x8 qf[2][4];
    #pragma unroll
    for (int mb = 0; mb < 2; mb++) {
        const unsigned short* qp =
            qb + ((size_t)(bh * S_ + wrow0 + mb * 16 + l16)) * HD_ + quad * 8;
        #pragma unroll
        for (int c = 0; c < 4; c++)
            qf[mb][c] = *(const bf16x8*)(qp + c * 32);
    }

    f32x4 of[2][8];
    #pragma unroll
    for (int mb = 0; mb < 2; mb++)
        #pragma unroll
        for (int db = 0; db < 8; db++)
            #pragma unroll
            for (int r = 0; r < 4; r++) of[mb][db][r] = 0.0f;
    float mr[2][4], lr[2][4];
    #pragma unroll
    for (int mb = 0; mb < 2; mb++)
        #pragma unroll
        for (int r = 0; r < 4; r++) { mr[mb][r] = -1e30f; lr[mb][r] = 0.0f; }

    // log2-domain softmax: scale' = (1/sqrt(128))*log2(e), mask' = -1e4*log2(e)
    const float scale2 = 0.12751744459892879f;
    const float mneg2  = -14426.950408889634f;

    // prefetch registers
    uint4 kr[4];
    uint4 v0a, v0b, v1a, v1b;

    auto issue_tile = [&](int kt2) {
        const int s2 = kt2 * 64;
        const unsigned short* kg = kb + ((size_t)(bh * S_ + s2 + krow)) * HD_ + kcb;
        #pragma unroll
        for (int u = 0; u < 4; u++) kr[u] = *(const uint4*)(kg + u * 8);
        const unsigned short* vg = vb + ((size_t)(bh * S_ + s2 + 2 * vq)) * HD_ + vd0;
        v0a = *(const uint4*)(vg);
        v0b = *(const uint4*)(vg + 8);
        v1a = *(const uint4*)(vg + HD_);
        v1b = *(const uint4*)(vg + HD_ + 8);
    };

    issue_tile(0);

    for (int kt = 0; kt < ntiles; kt++) {
        const int s0 = kt * 64;
        __syncthreads();                  // prior iter's LDS readers done
        // ---- K tile -> LDS (row-major, b128)
        #pragma unroll
        for (int u = 0; u < 4; u++)
            *(uint4*)&Ks[krow * KSTR + kcb + u * 8] = kr[u];
        // ---- V tile -> LDS transposed: Vt[d][s], s-pairs packed as b32
        {
            unsigned int r0[8] = { v0a.x, v0a.y, v0a.z, v0a.w,
                                   v0b.x, v0b.y, v0b.z, v0b.w };
            unsigned int r1[8] = { v1a.x, v1a.y, v1a.z, v1a.w,
                                   v1b.x, v1b.y, v1b.z, v1b.w };
            #pragma unroll
            for (int j = 0; j < 16; j++) {
                const int u = j >> 1;
                unsigned int pk;
                if ((j & 1) == 0)
                    pk = (r0[u] & 0xffffu) | (r1[u] << 16);
                else
                    pk = (r0[u] >> 16) | (r1[u] & 0xffff0000u);
                *(unsigned int*)&Vt[(vd0 + j) * VSTR + 2 * vq] = pk;
            }
        }
        __syncthreads();

        if (kt + 1 < ntiles) issue_tile(kt + 1);

        // ---- S = Q K^T : m-blocks x 4 nb; kf reused across m-blocks
        f32x4 sf[2][4];
        #pragma unroll
        for (int mb = 0; mb < 2; mb++)
            #pragma unroll
            for (int nb = 0; nb < 4; nb++)
                #pragma unroll
                for (int r = 0; r < 4; r++) sf[mb][nb][r] = 0.0f;
        #pragma unroll
        for (int c = 0; c < 4; c++) {
            #pragma unroll
            for (int nb = 0; nb < 4; nb++) {
                bf16x8 kf = *(const bf16x8*)&Ks[(nb * 16 + l16) * KSTR + c * 32 + quad * 8];
                #pragma unroll
                for (int mb = 0; mb < 2; mb++)
                    sf[mb][nb] = __builtin_amdgcn_mfma_f32_16x16x32_bf16(
                        qf[mb][c], kf, sf[mb][nb], 0, 0, 0);
            }
        }

        // ---- scale + causal mask, log2 domain
        const bool need_mask = (s0 + 63 > wrow0);
        #pragma unroll
        for (int mb = 0; mb < 2; mb++) {
            const int qr0 = wrow0 + mb * 16 + quad * 4;
            #pragma unroll
            for (int nb = 0; nb < 4; nb++) {
                const int kcol = s0 + nb * 16 + l16;
                #pragma unroll
                for (int r = 0; r < 4; r++) {
                    float s = sf[mb][nb][r] * scale2;
                    if (need_mask && kcol > qr0 + r) s += mneg2;
                    sf[mb][nb][r] = s;
                }
            }
        }

        // ---- online softmax per m-block (max reduce over 16-lane group;
        //      lr kept as per-lane partials; rescale deferred when max static)
        #pragma unroll
        for (int mb = 0; mb < 2; mb++) {
            float mt4[4];
            #pragma unroll
            for (int r = 0; r < 4; r++) {
                float mt = fmaxf(fmaxf(sf[mb][0][r], sf[mb][1][r]),
                                 fmaxf(sf[mb][2][r], sf[mb][3][r]));
                mt = fmaxf(mt, __shfl_xor(mt, 1));
                mt = fmaxf(mt, __shfl_xor(mt, 2));
                mt = fmaxf(mt, __shfl_xor(mt, 4));
                mt = fmaxf(mt, __shfl_xor(mt, 8));
                mt4[r] = mt;
            }
            const bool grew = (mt4[0] > mr[mb][0]) || (mt4[1] > mr[mb][1]) ||
                              (mt4[2] > mr[mb][2]) || (mt4[3] > mr[mb][3]);
            if (__any(grew)) {
                float alpha[4];
                #pragma unroll
                for (int r = 0; r < 4; r++) {
                    const float mnew = fmaxf(mr[mb][r], mt4[r]);
                    alpha[r] = __builtin_amdgcn_exp2f(mr[mb][r] - mnew);
                    mr[mb][r] = mnew;
                    lr[mb][r] *= alpha[r];
                }
                #pragma unroll
                for (int db = 0; db < 8; db++)
                    #pragma unroll
                    for (int r = 0; r < 4; r++) of[mb][db][r] *= alpha[r];
            }
            #pragma unroll
            for (int r = 0; r < 4; r++) {
                float rs = 0.0f;
                #pragma unroll
                for (int nb = 0; nb < 4; nb++) {
                    float p = __builtin_amdgcn_exp2f(sf[mb][nb][r] - mr[mb][r]);
                    sf[mb][nb][r] = p;
                    rs += p;
                }
                lr[mb][r] += rs;       // per-lane partial; reduced in epilogue
            }

            // P: C-layout -> wave-private LDS [m][s]
            #pragma unroll
            for (int nb = 0; nb < 4; nb++)
                #pragma unroll
                for (int r = 0; r < 4; r++)
                    Pw[(mb * 16 + quad * 4 + r) * PSTR + nb * 16 + l16] =
                        f2b(sf[mb][nb][r]);
        }

        // ---- O += P V : vf reused across m-blocks
        #pragma unroll
        for (int kc = 0; kc < 2; kc++) {
            bf16x8 pf[2];
            #pragma unroll
            for (int mb = 0; mb < 2; mb++)
                pf[mb] = *(const bf16x8*)&Pw[(mb * 16 + l16) * PSTR + kc * 32 + quad * 8];
            #pragma unroll
            for (int db = 0; db < 8; db++) {
                bf16x8 vf = *(const bf16x8*)&Vt[(db * 16 + l16) * VSTR + kc * 32 + quad * 8];
                #pragma unroll
                for (int mb = 0; mb < 2; mb++)
                    of[mb][db] = __builtin_amdgcn_mfma_f32_16x16x32_bf16(
                        pf[mb], vf, of[mb][db], 0, 0, 0);
            }
        }
    }

    // ---- epilogue: lane-reduce lr, normalize, LDS transpose, float4 stores.
    // One m-block per pass; barrier between passes (union WAR safety).
    float* Ow = sm.Ow + w * 16 * OSTR;     // wave-private 16x132 fp32
    #pragma unroll
    for (int mb = 0; mb < 2; mb++) {
        __syncthreads();                   // readers of Ks/Vt/Ps (or pass 0) done
        float inv[4];
        #pragma unroll
        for (int r = 0; r < 4; r++) {
            float ls = lr[mb][r];
            ls += __shfl_xor(ls, 1);
            ls += __shfl_xor(ls, 2);
            ls += __shfl_xor(ls, 4);
            ls += __shfl_xor(ls, 8);
            inv[r] = 1.0f / ls;
        }
        #pragma unroll
        for (int db = 0; db < 8; db++)
            #pragma unroll
            for (int r = 0; r < 4; r++)
                Ow[(quad * 4 + r) * OSTR + db * 16 + l16] = of[mb][db][r] * inv[r];
        #pragma unroll
        for (int rg = 0; rg < 4; rg++) {
            const int rowl = rg * 4 + quad;
            float* op = out + ((size_t)(b * S_ + wrow0 + mb * 16 + rowl)) * E_ + h * HD_;
            #pragma unroll
            for (int u = 0; u < 2; u++) {
                float4 v4 = *(const float4*)&Ow[rowl * OSTR + u * 64 + l16 * 4];
                *(float4*)(op + u * 64 + l16 * 4) = v4;
            }
        }
    }
}

// ---------------------------------------------------------------------------
extern "C" void kernel_launch(void* const* d_in, const int* in_sizes, int n_in,
                              void* d_out, int out_size, void* d_ws, size_t ws_size,
                              hipStream_t stream)
{
    const float* x    = (const float*)d_in[0];   // fp32 (B,S,E)
    const float* W    = (const float*)d_in[1];   // fp32 (6144,2048)
    const float* bias = (const float*)d_in[2];   // fp32 (6144,)
    float* out = (float*)d_out;                  // fp32 (B,S,E)

    const size_t per = (size_t)B_ * NH_ * S_ * HD_;               // 8388608
    unsigned short* qb = (unsigned short*)d_ws;                   // [B][NH][S][HD]
    unsigned short* kb = qb + per;                                // [B][NH][S][HD]
    unsigned short* vb = kb + per;                                // [B][NH][S][HD]
    unsigned short* Xb = vb + per;                                // bf16 X  (16.8 MB)
    unsigned short* Wb = Xb + (size_t)XN_;                        // bf16 W  (25.2 MB)

    const int cvt_elems = XN_ + NQKV_ * E_;                       // 20971520
    cvt_bf16<<<cvt_elems / (256 * 8), 256, 0, stream>>>(x, W, Xb);

    dim3 gemm_grid(NQKV_ / 128, M_ / 128);                        // 48 x 32
    qkv_gemm<<<gemm_grid, 256, 0, stream>>>(Xb, Wb, bias, qb, kb, vb);

    attn_mfma<<<dim3((S_ / 128) * B_ * NH_), 256, 0, stream>>>(qb, kb, vb, out);
}

// Round 3
// 366.003 us; speedup vs baseline: 1.3075x; 1.0425x over previous
//
#include <hip/hip_runtime.h>

// MHA: cvt fp32->bf16 -> QKV GEMM (bf16 MFMA, global_load_lds, fused RoPE)
//      -> MFMA flash attention (fp32 out)
// B=2 S=2048 E=2048 NH=16 HD=128 ROTARY=32 base=1e4 NEG_INF=-1e4
#define B_    2
#define S_    2048
#define E_    2048
#define NH_   16
#define HD_   128
#define NQKV_ 6144
#define M_    4096
#define XN_   (M_ * E_)          // 8388608 X elements

typedef short bf16x8 __attribute__((ext_vector_type(8)));   // 8 bf16 (4 VGPRs)
typedef float f32x4  __attribute__((ext_vector_type(4)));   // MFMA C/D

typedef const __attribute__((address_space(1))) void* gas_t; // global addrspace
typedef __attribute__((address_space(3))) void*       las_t; // LDS addrspace

__device__ inline float b2f(unsigned short u) {
    return __uint_as_float(((unsigned int)u) << 16);
}
__device__ inline unsigned short f2b(float f) {             // RNE f32->bf16
    unsigned int x = __float_as_uint(f);
    x = x + 0x7fffu + ((x >> 16) & 1u);
    return (unsigned short)(x >> 16);
}
__device__ inline unsigned int pk2(float lo, float hi) {
    return (unsigned int)f2b(lo) | ((unsigned int)f2b(hi) << 16);
}

// ---------------------------------------------------------------------------
// Kernel 0: one-shot fp32 -> bf16 of X (8.39M) and W (12.58M) into workspace.
// ---------------------------------------------------------------------------
__global__ __launch_bounds__(256) void cvt_bf16(
    const float* __restrict__ X,
    const float* __restrict__ W,
    unsigned short* __restrict__ O)      // [XN_ of X][W follows]
{
    const long i = (long)(blockIdx.x * 256 + threadIdx.x) * 8;
    const float* src = (i < XN_) ? (X + i) : (W + (i - XN_));
    const float4 a = *(const float4*)(src);
    const float4 b = *(const float4*)(src + 4);
    uint4 o = { pk2(a.x, a.y), pk2(a.z, a.w), pk2(b.x, b.y), pk2(b.z, b.w) };
    *(uint4*)(O + i) = o;
}

// ---------------------------------------------------------------------------
// Kernel 1: QKV = Xb(4096x2048 bf16) * Wb^T + bias, RoPE fused in epilogue.
// m97 structure: 128x128 tile, BK=32, double-buffered LDS via
// global_load_lds width=16. (unchanged from round 2)
// ---------------------------------------------------------------------------
__global__ __launch_bounds__(256, 2) void qkv_gemm(
    const unsigned short* __restrict__ Xb,   // bf16 [4096][2048]
    const unsigned short* __restrict__ Wb,   // bf16 [6144][2048]
    const float* __restrict__ bias,
    unsigned short* __restrict__ qb,
    unsigned short* __restrict__ kb,
    unsigned short* __restrict__ vb)
{
    __shared__ __align__(16) unsigned short As[2][128 * 32];  // 2 x 8 KB
    __shared__ __align__(16) unsigned short Bs[2][128 * 32];  // 2 x 8 KB

    const int t    = threadIdx.x;
    const int lane = t & 63;
    const int w    = t >> 6;
    const int m0   = blockIdx.y * 128;
    const int n0   = blockIdx.x * 128;
    const int wm   = (w >> 1) * 64;
    const int wn   = (w & 1) * 64;
    const int quad = lane >> 4;
    const int l16  = lane & 15;

    const unsigned short* Ag = Xb + (size_t)(m0 + (lane >> 2)) * E_ + (lane & 3) * 8;
    const unsigned short* Bg = Wb + (size_t)(n0 + (lane >> 2)) * E_ + (lane & 3) * 8;

    auto stage = [&](int bsel, int k0) {
        #pragma unroll
        for (int u = 0; u < 2; u++) {
            const int r0 = (w * 2 + u) * 16;               // wave-uniform
            __builtin_amdgcn_global_load_lds(
                (gas_t)(Ag + (size_t)r0 * E_ + k0),
                (las_t)&As[bsel][r0 * 32], 16, 0, 0);
            __builtin_amdgcn_global_load_lds(
                (gas_t)(Bg + (size_t)r0 * E_ + k0),
                (las_t)&Bs[bsel][r0 * 32], 16, 0, 0);
        }
    };

    f32x4 acc[4][4];
    #pragma unroll
    for (int i = 0; i < 4; i++)
        #pragma unroll
        for (int j = 0; j < 4; j++)
            #pragma unroll
            for (int r = 0; r < 4; r++) acc[i][j][r] = 0.0f;

    stage(0, 0);
    __syncthreads();
    int cur = 0;

    for (int k0 = 0; k0 < E_; k0 += 32) {
        if (k0 + 32 < E_) stage(cur ^ 1, k0 + 32);   // prefetch next K-tile

        bf16x8 af[4], bfr[4];
        #pragma unroll
        for (int i = 0; i < 4; i++)
            af[i]  = *(const bf16x8*)&As[cur][(wm + i * 16 + l16) * 32 + quad * 8];
        #pragma unroll
        for (int i = 0; i < 4; i++)
            bfr[i] = *(const bf16x8*)&Bs[cur][(wn + i * 16 + l16) * 32 + quad * 8];

        #pragma unroll
        for (int i = 0; i < 4; i++)
            #pragma unroll
            for (int j = 0; j < 4; j++)
                acc[i][j] = __builtin_amdgcn_mfma_f32_16x16x32_bf16(
                    af[i], bfr[j], acc[i][j], 0, 0, 0);

        __syncthreads();
        cur ^= 1;
    }

    const int nb0   = n0 + wn;
    const int which = nb0 >> 11;                  // 0=q 1=k 2=v (const/block)
    const int h     = (nb0 >> 7) & 15;
    unsigned short* dst = (which == 0) ? qb : ((which == 1) ? kb : vb);

    float bv[4];
    #pragma unroll
    for (int j = 0; j < 4; j++) bv[j] = bias[nb0 + j * 16 + l16];
    #pragma unroll
    for (int i = 0; i < 4; i++)
        #pragma unroll
        for (int j = 0; j < 4; j++)
            #pragma unroll
            for (int r = 0; r < 4; r++) acc[i][j][r] += bv[j];

    if (wn == 0 && which < 2) {                   // rope on q/k, d in [0,32)
        const float inv = exp2f(-0.83048202372184059f * (float)l16); // 1e4^(-d/16)
        #pragma unroll
        for (int i = 0; i < 4; i++) {
            #pragma unroll
            for (int r = 0; r < 4; r++) {
                const int m = m0 + wm + i * 16 + quad * 4 + r;
                const int s = m & (S_ - 1);
                float c, sn;
                __sincosf((float)s * inv, &sn, &c);
                const float u1 = acc[i][0][r], u2 = acc[i][1][r];
                acc[i][0][r] = u1 * c - u2 * sn;
                acc[i][1][r] = u1 * sn + u2 * c;
            }
        }
    }

    #pragma unroll
    for (int j = 0; j < 4; j++) {
        const int d = wn + j * 16 + l16;
        #pragma unroll
        for (int i = 0; i < 4; i++) {
            #pragma unroll
            for (int r = 0; r < 4; r++) {
                const int m  = m0 + wm + i * 16 + quad * 4 + r;  // 0..4095
                const int bb = m >> 11;
                const int s  = m & (S_ - 1);
                dst[((size_t)(bb * NH_ + h) * S_ + s) * HD_ + d] = f2b(acc[i][j][r]);
            }
        }
    }
}

// ---------------------------------------------------------------------------
// Kernel 2: MFMA causal flash attention. Round-2 restructure:
//  * q-block 128 -> 64 rows: grid 1024 (= 32 qt64 x 32 bh), heavy-first.
//    Round-1 grid (512 = exactly 2/CU resident, no backfill) measured
//    time-avg occupancy 13.2% = (avg work 17 / max 32) * 25% static.
//    1024 blocks + Ps halved (LDS 54.3 -> 45.0 KB -> 3 blocks/CU) gives
//    backfill + 37.5% static ceiling.
//  * wave owns 16 q-rows (mb loop removed); per-tile wave work: 16+16 MFMA.
//  * everything else (log2 softmax, defer-rescale, lr partials, reg
//    prefetch of K/V, LDS V-transpose, Ow epilogue) unchanged.
// Layouts (HW-verified 16x16x32_bf16): A[m=lane&15][k=quad*8+j];
// C/D row=quad*4+reg, col=lane&15.
// ---------------------------------------------------------------------------
#define KSTR 136
#define VSTR 72
#define PSTR 72
#define OSTR 132

__global__ __launch_bounds__(256, 3) void attn_mfma(
    const unsigned short* __restrict__ qb,
    const unsigned short* __restrict__ kb,
    const unsigned short* __restrict__ vb,
    float* __restrict__ out)
{
    union SM {
        struct {
            unsigned short Ks[64 * KSTR];      // 17408 B
            unsigned short Vt[128 * VSTR];     // 18432 B
            unsigned short Ps[4 * 16 * PSTR];  //  9216 B
        } a;                                   // 45056 B total
        float Ow[4 * 16 * OSTR];               // 33792 B (epilogue reuse)
    };
    __shared__ __align__(16) SM sm;
    unsigned short* Ks = sm.a.Ks;
    unsigned short* Vt = sm.a.Vt;
    unsigned short* Ps = sm.a.Ps;

    const int bid  = blockIdx.x;
    const int qt   = 31 - (bid >> 5);       // 64-row q-tile, heavy-first
    const int bh   = bid & 31;
    const int b    = bh >> 4;
    const int h    = bh & 15;
    const int t    = threadIdx.x;
    const int lane = t & 63;
    const int w    = t >> 6;
    const int quad = lane >> 4;
    const int l16  = lane & 15;

    const int wrow0  = qt * 64 + w * 16;    // wave q-row base (16 rows)
    const int ntiles = qt + 1;              // K tiles of 64

    unsigned short* Pw = Ps + w * 16 * PSTR;

    // staging maps (256 threads)
    const int krow = t >> 2, kcb = (t & 3) * 32;   // K: row, col-block
    const int vq   = t & 31, vd0 = (t >> 5) * 16;  // V: s-pair, d-block

    // Q A-fragments from global: k = c*32 + quad*8 + j
    bf16x8 qf[4];
    {
        const unsigned short* qp =
            qb + ((size_t)(bh * S_ + wrow0 + l16)) * HD_ + quad * 8;
        #pragma unroll
        for (int c = 0; c < 4; c++)
            qf[c] = *(const bf16x8*)(qp + c * 32);
    }

    f32x4 of[8];
    #pragma unroll
    for (int db = 0; db < 8; db++)
        #pragma unroll
        for (int r = 0; r < 4; r++) of[db][r] = 0.0f;
    float mr[4], lr[4];
    #pragma unroll
    for (int r = 0; r < 4; r++) { mr[r] = -1e30f; lr[r] = 0.0f; }

    // log2-domain softmax: scale' = (1/sqrt(128))*log2(e), mask' = -1e4*log2(e)
    const float scale2 = 0.12751744459892879f;
    const float mneg2  = -14426.950408889634f;

    // prefetch registers
    uint4 kr[4];
    uint4 v0a, v0b, v1a, v1b;

    auto issue_tile = [&](int kt2) {
        const int s2 = kt2 * 64;
        const unsigned short* kg = kb + ((size_t)(bh * S_ + s2 + krow)) * HD_ + kcb;
        #pragma unroll
        for (int u = 0; u < 4; u++) kr[u] = *(const uint4*)(kg + u * 8);
        const unsigned short* vg = vb + ((size_t)(bh * S_ + s2 + 2 * vq)) * HD_ + vd0;
        v0a = *(const uint4*)(vg);
        v0b = *(const uint4*)(vg + 8);
        v1a = *(const uint4*)(vg + HD_);
        v1b = *(const uint4*)(vg + HD_ + 8);
    };

    issue_tile(0);

    for (int kt = 0; kt < ntiles; kt++) {
        const int s0 = kt * 64;
        __syncthreads();                  // prior iter's LDS readers done
        // ---- K tile -> LDS (row-major, b128)
        #pragma unroll
        for (int u = 0; u < 4; u++)
            *(uint4*)&Ks[krow * KSTR + kcb + u * 8] = kr[u];
        // ---- V tile -> LDS transposed: Vt[d][s], s-pairs packed as b32
        {
            unsigned int r0[8] = { v0a.x, v0a.y, v0a.z, v0a.w,
                                   v0b.x, v0b.y, v0b.z, v0b.w };
            unsigned int r1[8] = { v1a.x, v1a.y, v1a.z, v1a.w,
                                   v1b.x, v1b.y, v1b.z, v1b.w };
            #pragma unroll
            for (int j = 0; j < 16; j++) {
                const int u = j >> 1;
                unsigned int pk;
                if ((j & 1) == 0)
                    pk = (r0[u] & 0xffffu) | (r1[u] << 16);
                else
                    pk = (r0[u] >> 16) | (r1[u] & 0xffff0000u);
                *(unsigned int*)&Vt[(vd0 + j) * VSTR + 2 * vq] = pk;
            }
        }
        __syncthreads();

        if (kt + 1 < ntiles) issue_tile(kt + 1);

        // ---- S = Q K^T : 4 nb MFMAs
        f32x4 sf[4];
        #pragma unroll
        for (int nb = 0; nb < 4; nb++)
            #pragma unroll
            for (int r = 0; r < 4; r++) sf[nb][r] = 0.0f;
        #pragma unroll
        for (int c = 0; c < 4; c++) {
            #pragma unroll
            for (int nb = 0; nb < 4; nb++) {
                bf16x8 kf = *(const bf16x8*)&Ks[(nb * 16 + l16) * KSTR + c * 32 + quad * 8];
                sf[nb] = __builtin_amdgcn_mfma_f32_16x16x32_bf16(
                    qf[c], kf, sf[nb], 0, 0, 0);
            }
        }

        // ---- scale + causal mask, log2 domain
        const bool need_mask = (s0 + 63 > wrow0);
        {
            const int qr0 = wrow0 + quad * 4;
            #pragma unroll
            for (int nb = 0; nb < 4; nb++) {
                const int kcol = s0 + nb * 16 + l16;
                #pragma unroll
                for (int r = 0; r < 4; r++) {
                    float s = sf[nb][r] * scale2;
                    if (need_mask && kcol > qr0 + r) s += mneg2;
                    sf[nb][r] = s;
                }
            }
        }

        // ---- online softmax (max reduce over 16-lane group; lr partials;
        //      rescale deferred when no row max grew)
        {
            float mt4[4];
            #pragma unroll
            for (int r = 0; r < 4; r++) {
                float mt = fmaxf(fmaxf(sf[0][r], sf[1][r]),
                                 fmaxf(sf[2][r], sf[3][r]));
                mt = fmaxf(mt, __shfl_xor(mt, 1));
                mt = fmaxf(mt, __shfl_xor(mt, 2));
                mt = fmaxf(mt, __shfl_xor(mt, 4));
                mt = fmaxf(mt, __shfl_xor(mt, 8));
                mt4[r] = mt;
            }
            const bool grew = (mt4[0] > mr[0]) || (mt4[1] > mr[1]) ||
                              (mt4[2] > mr[2]) || (mt4[3] > mr[3]);
            if (__any(grew)) {
                float alpha[4];
                #pragma unroll
                for (int r = 0; r < 4; r++) {
                    const float mnew = fmaxf(mr[r], mt4[r]);
                    alpha[r] = __builtin_amdgcn_exp2f(mr[r] - mnew);
                    mr[r] = mnew;
                    lr[r] *= alpha[r];
                }
                #pragma unroll
                for (int db = 0; db < 8; db++)
                    #pragma unroll
                    for (int r = 0; r < 4; r++) of[db][r] *= alpha[r];
            }
            #pragma unroll
            for (int r = 0; r < 4; r++) {
                float rs = 0.0f;
                #pragma unroll
                for (int nb = 0; nb < 4; nb++) {
                    float p = __builtin_amdgcn_exp2f(sf[nb][r] - mr[r]);
                    sf[nb][r] = p;
                    rs += p;
                }
                lr[r] += rs;       // per-lane partial; reduced in epilogue
            }

            // P: C-layout -> wave-private LDS [m][s]
            #pragma unroll
            for (int nb = 0; nb < 4; nb++)
                #pragma unroll
                for (int r = 0; r < 4; r++)
                    Pw[(quad * 4 + r) * PSTR + nb * 16 + l16] = f2b(sf[nb][r]);
        }

        // ---- O += P V
        #pragma unroll
        for (int kc = 0; kc < 2; kc++) {
            bf16x8 pf = *(const bf16x8*)&Pw[l16 * PSTR + kc * 32 + quad * 8];
            #pragma unroll
            for (int db = 0; db < 8; db++) {
                bf16x8 vf = *(const bf16x8*)&Vt[(db * 16 + l16) * VSTR + kc * 32 + quad * 8];
                of[db] = __builtin_amdgcn_mfma_f32_16x16x32_bf16(
                    pf, vf, of[db], 0, 0, 0);
            }
        }
    }

    // ---- epilogue: lane-reduce lr, normalize, LDS transpose, float4 stores.
    float* Ow = sm.Ow + w * 16 * OSTR;     // wave-private 16x132 fp32
    __syncthreads();                       // all readers of Ks/Vt/Ps done
    float inv[4];
    #pragma unroll
    for (int r = 0; r < 4; r++) {
        float ls = lr[r];
        ls += __shfl_xor(ls, 1);
        ls += __shfl_xor(ls, 2);
        ls += __shfl_xor(ls, 4);
        ls += __shfl_xor(ls, 8);
        inv[r] = 1.0f / ls;
    }
    #pragma unroll
    for (int db = 0; db < 8; db++)
        #pragma unroll
        for (int r = 0; r < 4; r++)
            Ow[(quad * 4 + r) * OSTR + db * 16 + l16] = of[db][r] * inv[r];
    #pragma unroll
    for (int rg = 0; rg < 4; rg++) {
        const int rowl = rg * 4 + quad;
        float* op = out + ((size_t)(b * S_ + wrow0 + rowl)) * E_ + h * HD_;
        #pragma unroll
        for (int u = 0; u < 2; u++) {
            float4 v4 = *(const float4*)&Ow[rowl * OSTR + u * 64 + l16 * 4];
            *(float4*)(op + u * 64 + l16 * 4) = v4;
        }
    }
}

// ---------------------------------------------------------------------------
extern "C" void kernel_launch(void* const* d_in, const int* in_sizes, int n_in,
                              void* d_out, int out_size, void* d_ws, size_t ws_size,
                              hipStream_t stream)
{
    const float* x    = (const float*)d_in[0];   // fp32 (B,S,E)
    const float* W    = (const float*)d_in[1];   // fp32 (6144,2048)
    const float* bias = (const float*)d_in[2];   // fp32 (6144,)
    float* out = (float*)d_out;                  // fp32 (B,S,E)

    const size_t per = (size_t)B_ * NH_ * S_ * HD_;               // 8388608
    unsigned short* qb = (unsigned short*)d_ws;                   // [B][NH][S][HD]
    unsigned short* kb = qb + per;                                // [B][NH][S][HD]
    unsigned short* vb = kb + per;                                // [B][NH][S][HD]
    unsigned short* Xb = vb + per;                                // bf16 X  (16.8 MB)
    unsigned short* Wb = Xb + (size_t)XN_;                        // bf16 W  (25.2 MB)

    const int cvt_elems = XN_ + NQKV_ * E_;                       // 20971520
    cvt_bf16<<<cvt_elems / (256 * 8), 256, 0, stream>>>(x, W, Xb);

    dim3 gemm_grid(NQKV_ / 128, M_ / 128);                        // 48 x 32
    qkv_gemm<<<gemm_grid, 256, 0, stream>>>(Xb, Wb, bias, qb, kb, vb);

    attn_mfma<<<dim3(32 * 32), 256, 0, stream>>>(qb, kb, vb, out);
}